// Round 7
// baseline (595.155 us; speedup 1.0000x reference)
//
#include <hip/hip_runtime.h>
#include <hip/hip_bf16.h>

typedef __bf16 bf16_t;
typedef __bf16 bf16x4 __attribute__((ext_vector_type(4)));
typedef __bf16 bf16x8 __attribute__((ext_vector_type(8)));
typedef float f32x4 __attribute__((ext_vector_type(4)));

#define GLOAD_LDS16(g, l)                                                      \
  __builtin_amdgcn_global_load_lds(                                            \
      (const __attribute__((address_space(1))) void*)(g),                      \
      (__attribute__((address_space(3))) void*)(l), 16, 0, 0)

#define MFMA(a, b, c) __builtin_amdgcn_mfma_f32_16x16x32_bf16((a), (b), (c), 0, 0, 0)

// ---------------------------------------------------------------------------
// ROUND 7: fat wave-tile + 2 blocks/CU.
// Tile BM=256 x BN=128, BK=32. 256 thr, 4 waves 2Mx2N, wave-tile 128x64
// (acc[8][4] = 128 regs; total ~216 < 256 -> 8 waves/CU = 2 blocks).
// LDS: 3 rotating bufs x (A[256][32] 16KB + B[128][32] 8KB) = 72KB ->
// 2 blocks/CU (144KB <= 160KB). Cross-block TLP hides barriers (r4 lesson);
// per-CU LDS-read/MFMA ratio now 578/516 cy -> 89% MfmaUtil ceiling
// (was 67% in r6's 64x64 wave shape).
// Pipeline: iter t reads buf t%3, stages tile t+2 into (t+2)%3; 6 loads/
// thread/K-tile; end-of-iter vmcnt(6) == tile t+1 landed, t+2 flying
// (never drains to 0, T4). Round-2-verified swizzle: 16B unit ^=
// ((row>>1)&3) on pre-swizzled GLOBAL source, linear LDS dest (m173);
// fragment reads use kg ^ ((R>>1)&3)  -> measured 0 bank conflicts.
// Per K-tile: P0 {8 ds_read; 3 stages; barrier; lgkm0; 16 MFMA mi0-3},
//             P1 {4 ds_read; 3 stages; barrier; lgkm0; 16 MFMA mi4-7;
//                 vmcnt(6); barrier}.
//
// u-only LISTA with T = I - S:  u' = soft_thresh(T@u) + Wx
// mode 0: UnextOrWx = bf16(acc)                       (Wx GEMM; u1 = Wx)
// mode 1: UnextOrWx = bf16(soft_thresh(acc) + WxIn)
// mode 2: z = soft_thresh(acc); fused transpose-write Out[b][k][p]
// ---------------------------------------------------------------------------
__global__ __launch_bounds__(256, 2) void gemm_kernel(
    const bf16_t* __restrict__ A, const bf16_t* __restrict__ Bt,
    int Kd, int mode,
    const bf16_t* __restrict__ WxIn, bf16_t* __restrict__ UnextOrWx,
    float* __restrict__ Out, const float* __restrict__ thresh_p)
{
  __shared__ __align__(16) char smem[73728];
  bf16_t* lds = (bf16_t*)smem;           // buf stride 12288 elems; B at +8192

  const int tid = threadIdx.x;
  const int wid = tid >> 6, lane = tid & 63;
  const int wr = wid >> 1, wc = wid & 1;         // 2M x 2N wave grid
  const int lr = lane & 15, kg = lane >> 4;

  // XCD-chunked swizzle (grid 1024 % 8 == 0), N-fastest: one XCD chunk =
  // 16 M-panels x all 8 N-tiles (A-panel shared in L2; B=T 2MiB resident).
  const int per = gridDim.x >> 3;
  const int logical = (blockIdx.x & 7) * per + (blockIdx.x >> 3);
  const int tileN = (logical & 7) << 7;          // 0..896
  const int tileM = (logical >> 3) << 8;         // 0..32512
  const int NT = Kd >> 5;

  // Per-thread staging geometry. A: 4 rounds, B: 2 rounds (16B units).
  size_t offA[4]; int dstA[4];
  #pragma unroll
  for (int j = 0; j < 4; ++j) {
    const int f = j * 256 + tid;                 // 0..1023
    const int row = f >> 2, u = f & 3;
    const int ug = u ^ ((row >> 1) & 3);
    offA[j] = (size_t)(tileM + row) * Kd + ug * 8;
    dstA[j] = f * 8;
  }
  size_t offB[2]; int dstB[2];
  #pragma unroll
  for (int j = 0; j < 2; ++j) {
    const int f = j * 256 + tid;                 // 0..511
    const int col = f >> 2, u = f & 3;
    const int ug = u ^ ((col >> 1) & 3);
    offB[j] = (size_t)(tileN + col) * Kd + ug * 8;
    dstB[j] = 8192 + f * 8;
  }

  auto readA = [&](int mi, int bs) -> bf16x8 {
    const int R = wr * 128 + mi * 16 + lr;
    return *(const bf16x8*)(lds + bs + R * 32 + ((kg ^ ((R >> 1) & 3)) << 3));
  };
  auto readB = [&](int ni, int bs) -> bf16x8 {
    const int C = wc * 64 + ni * 16 + lr;
    return *(const bf16x8*)(lds + bs + 8192 + C * 32 + ((kg ^ ((C >> 1) & 3)) << 3));
  };

  f32x4 acc[8][4] = {};
  bf16x8 af[4], bfr[4];

  // Prologue: stage tiles 0 and 1 (6 loads each).
  #pragma unroll
  for (int j = 0; j < 4; ++j) GLOAD_LDS16(A + offA[j], lds + dstA[j]);
  #pragma unroll
  for (int j = 0; j < 2; ++j) GLOAD_LDS16(Bt + offB[j], lds + dstB[j]);
  #pragma unroll
  for (int j = 0; j < 4; ++j) GLOAD_LDS16(A + offA[j] + 32, lds + 12288 + dstA[j]);
  #pragma unroll
  for (int j = 0; j < 2; ++j) GLOAD_LDS16(Bt + offB[j] + 32, lds + 12288 + dstB[j]);
  asm volatile("s_waitcnt vmcnt(6)" ::: "memory");   // tile 0 landed
  __builtin_amdgcn_s_barrier();

  int buf = 0, sb3 = 2;                              // t%3, (t+2)%3
  for (int t = 0; t < NT; ++t) {
    const int bs = buf * 12288;
    const int sbs = sb3 * 12288;
    const int ts = (t + 2 < NT) ? t + 2 : t + 2 - NT;   // wrap refetch (benign)
    const size_t ko = (size_t)ts << 5;

    // ---- P0: mi 0-3
    #pragma unroll
    for (int mi = 0; mi < 4; ++mi) af[mi] = readA(mi, bs);
    #pragma unroll
    for (int ni = 0; ni < 4; ++ni) bfr[ni] = readB(ni, bs);
    GLOAD_LDS16(A + offA[0] + ko, lds + sbs + dstA[0]);
    GLOAD_LDS16(A + offA[1] + ko, lds + sbs + dstA[1]);
    GLOAD_LDS16(A + offA[2] + ko, lds + sbs + dstA[2]);
    __builtin_amdgcn_s_barrier();
    asm volatile("s_waitcnt lgkmcnt(0)" ::: "memory");
    __builtin_amdgcn_sched_barrier(0);
    __builtin_amdgcn_s_setprio(1);
    #pragma unroll
    for (int mi = 0; mi < 4; ++mi)
      #pragma unroll
      for (int ni = 0; ni < 4; ++ni)
        acc[mi][ni] = MFMA(af[mi], bfr[ni], acc[mi][ni]);
    __builtin_amdgcn_s_setprio(0);

    // ---- P1: mi 4-7
    #pragma unroll
    for (int mi = 0; mi < 4; ++mi) af[mi] = readA(mi + 4, bs);
    GLOAD_LDS16(A + offA[3] + ko, lds + sbs + dstA[3]);
    GLOAD_LDS16(Bt + offB[0] + ko, lds + sbs + dstB[0]);
    GLOAD_LDS16(Bt + offB[1] + ko, lds + sbs + dstB[1]);
    __builtin_amdgcn_s_barrier();
    asm volatile("s_waitcnt lgkmcnt(0)" ::: "memory");
    __builtin_amdgcn_sched_barrier(0);
    __builtin_amdgcn_s_setprio(1);
    #pragma unroll
    for (int mi = 0; mi < 4; ++mi)
      #pragma unroll
      for (int ni = 0; ni < 4; ++ni)
        acc[mi + 4][ni] = MFMA(af[mi], bfr[ni], acc[mi + 4][ni]);
    __builtin_amdgcn_s_setprio(0);
    asm volatile("s_waitcnt vmcnt(6)" ::: "memory");   // tile t+1 landed
    __builtin_amdgcn_s_barrier();

    buf = (buf == 2) ? 0 : buf + 1;
    sb3 = (sb3 == 2) ? 0 : sb3 + 1;
  }

  const float th = *thresh_p;

  if (mode <= 1) {
    // Repack epilogue: canonical row-major bf16, 8B/lane full-line stores.
    asm volatile("s_waitcnt vmcnt(0)" ::: "memory");   // wrap stages landed
    __syncthreads();
    float* Tl = (float*)smem;                          // [32][132] f32
    #pragma unroll
    for (int c = 0; c < 8; ++c) {                      // 32-row chunks
      if (c) __syncthreads();
      if (wr == (c >> 2)) {
        #pragma unroll
        for (int mj = 0; mj < 2; ++mj) {
          const int mi = (c & 3) * 2 + mj;
          const int rl = mj * 16 + kg * 4;
          #pragma unroll
          for (int ni = 0; ni < 4; ++ni) {
            const int cl = wc * 64 + ni * 16 + lr;
            #pragma unroll
            for (int r = 0; r < 4; ++r)
              Tl[(rl + r) * 132 + cl] = acc[mi][ni][r];
          }
        }
      }
      __syncthreads();
      #pragma unroll
      for (int j = 0; j < 4; ++j) {
        const int f  = j * 256 + tid;                  // 0..1023
        const int rl = f >> 5;                         // 0..31
        const int c4 = (f & 31) * 4;                   // 0..124
        const f32x4 v = *(const f32x4*)&Tl[rl * 132 + c4];
        const int grow = tileM + c * 32 + rl;
        const size_t gidx = (size_t)grow * 1024 + tileN + c4;
        bf16x4 ov;
        if (mode == 1) {
          const bf16x4 wx = *(const bf16x4*)&WxIn[gidx];
          #pragma unroll
          for (int e = 0; e < 4; ++e) {
            const float a  = fabsf(v[e]) - th;
            const float zn = (a > 0.f) ? copysignf(a, v[e]) : 0.f;
            ov[e] = (bf16_t)(zn + (float)wx[e]);
          }
        } else {
          #pragma unroll
          for (int e = 0; e < 4; ++e) ov[e] = (bf16_t)v[e];
        }
        *(bf16x4*)&UnextOrWx[gidx] = ov;
      }
    }
  } else {
    // mode 2: z = st(acc), fused transpose via LDS -> Out[b][k][p], f32 16B.
    #pragma unroll
    for (int mi = 0; mi < 8; ++mi)
      #pragma unroll
      for (int ni = 0; ni < 4; ++ni)
        #pragma unroll
        for (int r = 0; r < 4; ++r) {
          const float v = acc[mi][ni][r];
          const float a = fabsf(v) - th;
          acc[mi][ni][r] = (a > 0.f) ? copysignf(a, v) : 0.f;
        }
    asm volatile("s_waitcnt vmcnt(0)" ::: "memory");
    __syncthreads();
    float* T = (float*)smem;                           // [32][260] f32
    const int    bb    = tileM >> 10;
    const size_t obase = (size_t)bb * 1048576 + (size_t)(tileM & 1023);
    #pragma unroll
    for (int ch = 0; ch < 4; ++ch) {                   // 32-k-col chunks
      if (ch) __syncthreads();
      if (wc == (ch >> 1)) {
        #pragma unroll
        for (int nj = 0; nj < 2; ++nj) {
          const int ni = (ch & 1) * 2 + nj;
          const int cp = nj * 16 + lr;                 // 0..31
          #pragma unroll
          for (int mi = 0; mi < 8; ++mi)
            #pragma unroll
            for (int r = 0; r < 4; ++r)
              T[cp * 260 + wr * 128 + mi * 16 + kg * 4 + r] = acc[mi][ni][r];
        }
      }
      __syncthreads();
      #pragma unroll
      for (int j = 0; j < 8; ++j) {
        const int f  = j * 256 + tid;                  // 0..2047
        const int cp = f >> 6;                         // 0..31
        const int p4 = (f & 63) * 4;                   // 0..252
        const f32x4 v = *(const f32x4*)&T[cp * 260 + p4];
        *(f32x4*)&Out[obase + (size_t)(tileN + ch * 32 + cp) * 1024 + p4] = v;
      }
    }
  }
}

__global__ void cast_f32_bf16_kernel(const float* __restrict__ src,
                                     bf16_t* __restrict__ dst, int n) {
  int i = blockIdx.x * blockDim.x + threadIdx.x;
  if (i < n) dst[i] = (bf16_t)src[i];
}

// T = I - S, cast to bf16. [1024][1024]
__global__ void make_T_kernel(const float* __restrict__ S,
                              bf16_t* __restrict__ T) {
  const int idx = blockIdx.x * blockDim.x + threadIdx.x;   // 0..1048575
  const int i = idx >> 10, j = idx & 1023;
  T[idx] = (bf16_t)(((i == j) ? 1.0f : 0.0f) - S[idx]);
}

// x [B][C=512][P=1024] f32 -> xt [b*1024+p][c] bf16  (32x32 tiled transpose)
__global__ void transpose_cast_x_kernel(const float* __restrict__ x,
                                        bf16_t* __restrict__ xt) {
  __shared__ float t[32][33];
  const int b  = blockIdx.z;
  const int p0 = blockIdx.x * 32;
  const int c0 = blockIdx.y * 32;
  const int tx = threadIdx.x, ty = threadIdx.y;
  #pragma unroll
  for (int i = 0; i < 32; i += 8)
    t[ty + i][tx] = x[((size_t)b * 512 + c0 + ty + i) * 1024 + p0 + tx];
  __syncthreads();
  #pragma unroll
  for (int i = 0; i < 32; i += 8)
    xt[((size_t)b * 1024 + p0 + ty + i) * 512 + c0 + tx] = (bf16_t)t[tx][ty + i];
}

__global__ void dict_norm_kernel(const float* __restrict__ dict,
                                 float* __restrict__ out) {
  const int row = blockIdx.x;       // 1024
  const int tid = threadIdx.x;      // 256
  const float* r = dict + (size_t)row * 512;
  float s = 0.f;
  for (int i = tid; i < 512; i += 256) { float v = r[i]; s += v * v; }
  #pragma unroll
  for (int off = 32; off > 0; off >>= 1) s += __shfl_down(s, off);
  __shared__ float ps[4];
  if ((tid & 63) == 0) ps[tid >> 6] = s;
  __syncthreads();
  const float inv = 1.0f / sqrtf(ps[0] + ps[1] + ps[2] + ps[3]);
  for (int i = tid; i < 512; i += 256) out[(size_t)row * 512 + i] = r[i] * inv;
}

extern "C" void kernel_launch(void* const* d_in, const int* in_sizes, int n_in,
                              void* d_out, int out_size, void* d_ws, size_t ws_size,
                              hipStream_t stream) {
  const float* x      = (const float*)d_in[0];  // [32,512,32,32]
  const float* dict   = (const float*)d_in[1];  // [1024,512]
  const float* W      = (const float*)d_in[2];  // [1024,512]
  const float* S      = (const float*)d_in[3];  // [1024,1024]
  const float* thresh = (const float*)d_in[4];  // scalar

  float* out = (float*)d_out;

  char* ws = (char*)d_ws;
  bf16_t* uA   = (bf16_t*)ws;                     //  67,108,864 B [32768][1024]
  bf16_t* uB   = (bf16_t*)(ws + 67108864);        //  67,108,864 B
  bf16_t* WxBf = (bf16_t*)(ws + 134217728);       //  67,108,864 B
  bf16_t* xt   = (bf16_t*)(ws + 201326592);       //  33,554,432 B [32768][512]
  bf16_t* Wbf  = (bf16_t*)(ws + 234881024);       //   1,048,576 B
  bf16_t* Tbf  = (bf16_t*)(ws + 235929600);       //   2,097,152 B (end 238,026,752)

  float* dnorm = out + 33554432;                  // dict_norm region (disjoint)

  cast_f32_bf16_kernel<<<dim3(2048), dim3(256), 0, stream>>>(W, Wbf, 524288);
  make_T_kernel<<<dim3(2048), dim3(512), 0, stream>>>(S, Tbf);
  transpose_cast_x_kernel<<<dim3(32, 16, 32), dim3(32, 8), 0, stream>>>(x, xt);
  dict_norm_kernel<<<dim3(1024), dim3(256), 0, stream>>>(dict, dnorm);

  // Wx_t = x_t @ W^T  -> WxBf  (u1 == Wx, read directly by step 1)
  gemm_kernel<<<dim3(1024), dim3(256), 0, stream>>>(
      xt, Wbf, 512, 0, nullptr, WxBf, nullptr, thresh);

  // steps 1..4: u' = soft_thresh(T@u) + Wx
  bf16_t* uc = WxBf; bf16_t* un = uA;
  for (int s = 0; s < 4; ++s) {
    gemm_kernel<<<dim3(1024), dim3(256), 0, stream>>>(
        uc, Tbf, 1024, 1, WxBf, un, nullptr, thresh);
    uc = un;
    un = (uc == uA) ? uB : uA;
  }
  // step 5: z = soft_thresh(T@u), fused transpose to out[b][k][p]
  gemm_kernel<<<dim3(1024), dim3(256), 0, stream>>>(
      uc, Tbf, 1024, 2, nullptr, nullptr, out, thresh);
}

// Round 8
// 557.973 us; speedup vs baseline: 1.0666x; 1.0666x over previous
//
#include <hip/hip_runtime.h>
#include <hip/hip_bf16.h>

typedef __bf16 bf16_t;
typedef __bf16 bf16x4 __attribute__((ext_vector_type(4)));
typedef __bf16 bf16x8 __attribute__((ext_vector_type(8)));
typedef float f32x4 __attribute__((ext_vector_type(4)));

#define GLOAD_LDS16(g, l)                                                      \
  __builtin_amdgcn_global_load_lds(                                            \
      (const __attribute__((address_space(1))) void*)(g),                      \
      (__attribute__((address_space(3))) void*)(l), 16, 0, 0)

#define MFMA(a, b, c) __builtin_amdgcn_mfma_f32_16x16x32_bf16((a), (b), (c), 0, 0, 0)

// ---------------------------------------------------------------------------
// ROUND 8 = ROUND 6 (best: 104us step) minus over-synchronization.
// Tile BM=256 x BN=128, BK=64. 512 thr, 8 waves 4Mx2N, wave-tile 64x64.
// LDS: 3 rotating bufs x (A[256][64] 32KB + B[128][64] 16KB) = 144KB.
// Iter t: issue ALL 6 stage loads for tile t+2 first (issue-early, T14),
// then plain-load fragments + MFMA for ks0/ks1 with NO barriers, NO lgkm
// drains, NO sched_barrier pins: fragment reads are plain LDS loads whose
// deps the compiler tracks with fine-grained counted lgkmcnt (m97 evidence);
// distinct ks0/ks1 frag regs let ks0-MFMA overlap ks1-ds_reads.
// The ONLY cross-wave sync: end-of-iter vmcnt(6) ("tile t+1 landed,
// t+2 flying" -- 12 outstanding -> 6; never drains to 0, T4) +
// __syncthreads() (full fence: nothing hoists across; also protects buffer
// reuse (t+2)%3 == (t-1)%3 against late readers).
// Swizzle (round-2 measured 0 conflicts): 16B unit ^ (row&7) applied on
// pre-swizzled GLOBAL source, linear LDS dest (m173); reads use
// (ks*4+kg)^(R&7).
//
// u-only LISTA with T = I - S:  u' = soft_thresh(T@u) + Wx
// mode 0: UnextOrWx = bf16(acc)                       (Wx GEMM; u1 = Wx)
// mode 1: UnextOrWx = bf16(soft_thresh(acc) + WxIn)
// mode 2: z = soft_thresh(acc); fused transpose-write Out[b][k][p]
// ---------------------------------------------------------------------------
__global__ __launch_bounds__(512, 2) void gemm_kernel(
    const bf16_t* __restrict__ A, const bf16_t* __restrict__ Bt,
    int Kd, int mode,
    const bf16_t* __restrict__ WxIn, bf16_t* __restrict__ UnextOrWx,
    float* __restrict__ Out, const float* __restrict__ thresh_p)
{
  __shared__ __align__(16) char smem[147456];
  bf16_t* lds = (bf16_t*)smem;           // buf stride 24576 elems; B at +16384

  const int tid = threadIdx.x;
  const int wid = tid >> 6, lane = tid & 63;
  const int wr = wid >> 1, wc = wid & 1;         // 4M x 2N wave grid
  const int lr = lane & 15, kg = lane >> 4;

  // XCD-chunked swizzle (grid 1024 % 8 == 0), N-fastest: 8 consecutive
  // logical blocks = one M-panel x all 8 N-tiles (share A panel; B=T 2MiB
  // L2-resident).
  const int per = gridDim.x >> 3;
  const int logical = (blockIdx.x & 7) * per + (blockIdx.x >> 3);
  const int tileN = (logical & 7) << 7;          // 0..896
  const int tileM = (logical >> 3) << 8;         // 0..32512
  const int NT = Kd >> 6;

  // Per-thread staging geometry (A: 4 rounds, B: 2 rounds of 16B units).
  size_t offA[4]; int dstA[4];
  #pragma unroll
  for (int j = 0; j < 4; ++j) {
    const int f = j * 512 + tid;                 // 0..2047
    const int row = f >> 3, u = f & 7;
    const int ug = u ^ (row & 7);
    offA[j] = (size_t)(tileM + row) * Kd + ug * 8;
    dstA[j] = f * 8;
  }
  size_t offB[2]; int dstB[2];
  #pragma unroll
  for (int j = 0; j < 2; ++j) {
    const int f = j * 512 + tid;                 // 0..1023
    const int col = f >> 3, u = f & 7;
    const int ug = u ^ (col & 7);
    offB[j] = (size_t)(tileN + col) * Kd + ug * 8;
    dstB[j] = 16384 + f * 8;
  }

  auto readA = [&](int mi, int ks, int bs) -> bf16x8 {
    const int R = wr * 64 + mi * 16 + lr;
    const int ul = (ks * 4 + kg) ^ (R & 7);
    return *(const bf16x8*)(lds + bs + R * 64 + ul * 8);
  };
  auto readB = [&](int ni, int ks, int bs) -> bf16x8 {
    const int C = wc * 64 + ni * 16 + lr;
    const int ul = (ks * 4 + kg) ^ (C & 7);
    return *(const bf16x8*)(lds + bs + 16384 + C * 64 + ul * 8);
  };

  f32x4 acc[4][4] = {};
  bf16x8 a0[4], b0[4], a1[4], b1[4];

  // Prologue: stage tiles 0 and 1 (6 loads each).
  #pragma unroll
  for (int j = 0; j < 4; ++j) GLOAD_LDS16(A + offA[j], lds + dstA[j]);
  #pragma unroll
  for (int j = 0; j < 2; ++j) GLOAD_LDS16(Bt + offB[j], lds + dstB[j]);
  if (NT > 1) {
    #pragma unroll
    for (int j = 0; j < 4; ++j) GLOAD_LDS16(A + offA[j] + 64, lds + 24576 + dstA[j]);
    #pragma unroll
    for (int j = 0; j < 2; ++j) GLOAD_LDS16(Bt + offB[j] + 64, lds + 24576 + dstB[j]);
  }
  asm volatile("s_waitcnt vmcnt(6)" ::: "memory");   // tile 0 landed
  __syncthreads();

  int buf = 0, sb3 = 2;                              // t%3, (t+2)%3
  for (int t = 0; t < NT; ++t) {
    const int bs = buf * 24576;
    const int sbs = sb3 * 24576;
    const int ts = (t + 2 < NT) ? t + 2 : t + 2 - NT;   // wrap refetch (benign)
    const size_t ko = (size_t)ts << 6;

    // Issue-early: all 6 stage loads for tile t+2.
    GLOAD_LDS16(A + offA[0] + ko, lds + sbs + dstA[0]);
    GLOAD_LDS16(A + offA[1] + ko, lds + sbs + dstA[1]);
    GLOAD_LDS16(A + offA[2] + ko, lds + sbs + dstA[2]);
    GLOAD_LDS16(A + offA[3] + ko, lds + sbs + dstA[3]);
    GLOAD_LDS16(Bt + offB[0] + ko, lds + sbs + dstB[0]);
    GLOAD_LDS16(Bt + offB[1] + ko, lds + sbs + dstB[1]);

    // ks = 0 fragments + MFMA (compiler schedules waits; may overlap below)
    #pragma unroll
    for (int mi = 0; mi < 4; ++mi) a0[mi] = readA(mi, 0, bs);
    #pragma unroll
    for (int ni = 0; ni < 4; ++ni) b0[ni] = readB(ni, 0, bs);
    // ks = 1 fragments (independent regs -> ks0 MFMA can overlap these reads)
    #pragma unroll
    for (int mi = 0; mi < 4; ++mi) a1[mi] = readA(mi, 1, bs);
    #pragma unroll
    for (int ni = 0; ni < 4; ++ni) b1[ni] = readB(ni, 1, bs);

    #pragma unroll
    for (int mi = 0; mi < 4; ++mi)
      #pragma unroll
      for (int ni = 0; ni < 4; ++ni)
        acc[mi][ni] = MFMA(a0[mi], b0[ni], acc[mi][ni]);
    #pragma unroll
    for (int mi = 0; mi < 4; ++mi)
      #pragma unroll
      for (int ni = 0; ni < 4; ++ni)
        acc[mi][ni] = MFMA(a1[mi], b1[ni], acc[mi][ni]);

    asm volatile("s_waitcnt vmcnt(6)" ::: "memory");   // tile t+1 landed
    __syncthreads();                                   // cross-wave visibility

    buf = (buf == 2) ? 0 : buf + 1;
    sb3 = (sb3 == 2) ? 0 : sb3 + 1;
  }

  const float th = *thresh_p;

  if (mode <= 1) {
    // Repack epilogue: canonical row-major bf16, 8B/lane full-line stores.
    asm volatile("s_waitcnt vmcnt(0)" ::: "memory");   // wrap stages landed
    __syncthreads();
    float* Tl = (float*)smem;                          // [32][132] f32
    #pragma unroll
    for (int c = 0; c < 8; ++c) {                      // 32-row chunks
      if (c) __syncthreads();
      if (wr == (c >> 1)) {
        #pragma unroll
        for (int mj = 0; mj < 2; ++mj) {
          const int mi = (c & 1) * 2 + mj;
          const int rl = mj * 16 + kg * 4;
          #pragma unroll
          for (int ni = 0; ni < 4; ++ni) {
            const int cl = wc * 64 + ni * 16 + lr;
            #pragma unroll
            for (int r = 0; r < 4; ++r)
              Tl[(rl + r) * 132 + cl] = acc[mi][ni][r];
          }
        }
      }
      __syncthreads();
      #pragma unroll
      for (int j = 0; j < 2; ++j) {
        const int f  = j * 512 + tid;                  // 0..1023
        const int rl = f >> 5;                         // 0..31
        const int c4 = (f & 31) * 4;                   // 0..124
        const f32x4 v = *(const f32x4*)&Tl[rl * 132 + c4];
        const int grow = tileM + c * 32 + rl;
        const size_t gidx = (size_t)grow * 1024 + tileN + c4;
        bf16x4 ov;
        if (mode == 1) {
          const bf16x4 wx = *(const bf16x4*)&WxIn[gidx];
          #pragma unroll
          for (int e = 0; e < 4; ++e) {
            const float a  = fabsf(v[e]) - th;
            const float zn = (a > 0.f) ? copysignf(a, v[e]) : 0.f;
            ov[e] = (bf16_t)(zn + (float)wx[e]);
          }
        } else {
          #pragma unroll
          for (int e = 0; e < 4; ++e) ov[e] = (bf16_t)v[e];
        }
        *(bf16x4*)&UnextOrWx[gidx] = ov;
      }
    }
  } else {
    // mode 2: z = st(acc), fused transpose via LDS -> Out[b][k][p], f32 16B.
    #pragma unroll
    for (int mi = 0; mi < 4; ++mi)
      #pragma unroll
      for (int ni = 0; ni < 4; ++ni)
        #pragma unroll
        for (int r = 0; r < 4; ++r) {
          const float v = acc[mi][ni][r];
          const float a = fabsf(v) - th;
          acc[mi][ni][r] = (a > 0.f) ? copysignf(a, v) : 0.f;
        }
    asm volatile("s_waitcnt vmcnt(0)" ::: "memory");
    __syncthreads();
    float* T = (float*)smem;                           // [32][260] f32
    const int    bb    = tileM >> 10;
    const size_t obase = (size_t)bb * 1048576 + (size_t)(tileM & 1023);
    #pragma unroll
    for (int ch = 0; ch < 4; ++ch) {                   // 32-k-col chunks
      if (ch) __syncthreads();
      if (wc == (ch >> 1)) {
        #pragma unroll
        for (int nj = 0; nj < 2; ++nj) {
          const int ni = (ch & 1) * 2 + nj;
          const int cp = nj * 16 + lr;                 // 0..31
          #pragma unroll
          for (int mi = 0; mi < 4; ++mi)
            #pragma unroll
            for (int r = 0; r < 4; ++r)
              T[cp * 260 + wr * 64 + mi * 16 + kg * 4 + r] = acc[mi][ni][r];
        }
      }
      __syncthreads();
      #pragma unroll
      for (int j = 0; j < 4; ++j) {
        const int f  = j * 512 + tid;                  // 0..2047
        const int cp = f >> 6;                         // 0..31
        const int p4 = (f & 63) * 4;                   // 0..252
        const f32x4 v = *(const f32x4*)&T[cp * 260 + p4];
        *(f32x4*)&Out[obase + (size_t)(tileN + ch * 32 + cp) * 1024 + p4] = v;
      }
    }
  }
}

__global__ void cast_f32_bf16_kernel(const float* __restrict__ src,
                                     bf16_t* __restrict__ dst, int n) {
  int i = blockIdx.x * blockDim.x + threadIdx.x;
  if (i < n) dst[i] = (bf16_t)src[i];
}

// T = I - S, cast to bf16. [1024][1024]
__global__ void make_T_kernel(const float* __restrict__ S,
                              bf16_t* __restrict__ T) {
  const int idx = blockIdx.x * blockDim.x + threadIdx.x;   // 0..1048575
  const int i = idx >> 10, j = idx & 1023;
  T[idx] = (bf16_t)(((i == j) ? 1.0f : 0.0f) - S[idx]);
}

// x [B][C=512][P=1024] f32 -> xt [b*1024+p][c] bf16  (32x32 tiled transpose)
__global__ void transpose_cast_x_kernel(const float* __restrict__ x,
                                        bf16_t* __restrict__ xt) {
  __shared__ float t[32][33];
  const int b  = blockIdx.z;
  const int p0 = blockIdx.x * 32;
  const int c0 = blockIdx.y * 32;
  const int tx = threadIdx.x, ty = threadIdx.y;
  #pragma unroll
  for (int i = 0; i < 32; i += 8)
    t[ty + i][tx] = x[((size_t)b * 512 + c0 + ty + i) * 1024 + p0 + tx];
  __syncthreads();
  #pragma unroll
  for (int i = 0; i < 32; i += 8)
    xt[((size_t)b * 1024 + p0 + ty + i) * 512 + c0 + tx] = (bf16_t)t[tx][ty + i];
}

__global__ void dict_norm_kernel(const float* __restrict__ dict,
                                 float* __restrict__ out) {
  const int row = blockIdx.x;       // 1024
  const int tid = threadIdx.x;      // 256
  const float* r = dict + (size_t)row * 512;
  float s = 0.f;
  for (int i = tid; i < 512; i += 256) { float v = r[i]; s += v * v; }
  #pragma unroll
  for (int off = 32; off > 0; off >>= 1) s += __shfl_down(s, off);
  __shared__ float ps[4];
  if ((tid & 63) == 0) ps[tid >> 6] = s;
  __syncthreads();
  const float inv = 1.0f / sqrtf(ps[0] + ps[1] + ps[2] + ps[3]);
  for (int i = tid; i < 512; i += 256) out[(size_t)row * 512 + i] = r[i] * inv;
}

extern "C" void kernel_launch(void* const* d_in, const int* in_sizes, int n_in,
                              void* d_out, int out_size, void* d_ws, size_t ws_size,
                              hipStream_t stream) {
  const float* x      = (const float*)d_in[0];  // [32,512,32,32]
  const float* dict   = (const float*)d_in[1];  // [1024,512]
  const float* W      = (const float*)d_in[2];  // [1024,512]
  const float* S      = (const float*)d_in[3];  // [1024,1024]
  const float* thresh = (const float*)d_in[4];  // scalar

  float* out = (float*)d_out;

  char* ws = (char*)d_ws;
  bf16_t* uA   = (bf16_t*)ws;                     //  67,108,864 B [32768][1024]
  bf16_t* uB   = (bf16_t*)(ws + 67108864);        //  67,108,864 B
  bf16_t* WxBf = (bf16_t*)(ws + 134217728);       //  67,108,864 B
  bf16_t* xt   = (bf16_t*)(ws + 201326592);       //  33,554,432 B [32768][512]
  bf16_t* Wbf  = (bf16_t*)(ws + 234881024);       //   1,048,576 B
  bf16_t* Tbf  = (bf16_t*)(ws + 235929600);       //   2,097,152 B (end 238,026,752)

  float* dnorm = out + 33554432;                  // dict_norm region (disjoint)

  cast_f32_bf16_kernel<<<dim3(2048), dim3(256), 0, stream>>>(W, Wbf, 524288);
  make_T_kernel<<<dim3(2048), dim3(512), 0, stream>>>(S, Tbf);
  transpose_cast_x_kernel<<<dim3(32, 16, 32), dim3(32, 8), 0, stream>>>(x, xt);
  dict_norm_kernel<<<dim3(1024), dim3(256), 0, stream>>>(dict, dnorm);

  // Wx_t = x_t @ W^T  -> WxBf  (u1 == Wx, read directly by step 1)
  gemm_kernel<<<dim3(1024), dim3(512), 0, stream>>>(
      xt, Wbf, 512, 0, nullptr, WxBf, nullptr, thresh);

  // steps 1..4: u' = soft_thresh(T@u) + Wx
  bf16_t* uc = WxBf; bf16_t* un = uA;
  for (int s = 0; s < 4; ++s) {
    gemm_kernel<<<dim3(1024), dim3(512), 0, stream>>>(
        uc, Tbf, 1024, 1, WxBf, un, nullptr, thresh);
    uc = un;
    un = (uc == uA) ? uB : uA;
  }
  // step 5: z = soft_thresh(T@u), fused transpose to out[b][k][p]
  gemm_kernel<<<dim3(1024), dim3(512), 0, stream>>>(
      uc, Tbf, 1024, 2, nullptr, nullptr, out, thresh);
}

// Round 9
// 550.976 us; speedup vs baseline: 1.0802x; 1.0127x over previous
//
#include <hip/hip_runtime.h>
#include <hip/hip_bf16.h>

typedef __bf16 bf16_t;
typedef __bf16 bf16x4 __attribute__((ext_vector_type(4)));
typedef __bf16 bf16x8 __attribute__((ext_vector_type(8)));
typedef float f32x4 __attribute__((ext_vector_type(4)));

#define GLOAD_LDS16(g, l)                                                      \
  __builtin_amdgcn_global_load_lds(                                            \
      (const __attribute__((address_space(1))) void*)(g),                      \
      (__attribute__((address_space(3))) void*)(l), 16, 0, 0)

#define MFMA(a, b, c) __builtin_amdgcn_mfma_f32_16x16x32_bf16((a), (b), (c), 0, 0, 0)

// ---------------------------------------------------------------------------
// ROUND 9 = ROUND 8 structure, BK 64 -> 32 for 2 blocks/CU.
// Tile BM=256 x BN=128, BK=32. 512 thr, 8 waves 4Mx2N, wave-tile 64x64.
// LDS: 3 rotating bufs x (A[256][32] 16KB + B[128][32] 8KB) = 72KB
// -> 2 blocks/CU (144KB <= 160KB), 16 waves/CU (launch_bounds 512,4).
// MECHANISM: r6/r8 at 1 block/CU had all 8 waves lockstepped by the
// end-of-iter barrier -> LDS-read phase and MFMA phase serialize on the
// same waves (MfmaUtil 26%). Two desynced blocks/CU fill each other's
// idle pipe (m114 cross-wave overlap; r4-vs-r6 cross-round evidence).
// Pipeline: iter t reads buf t%3, stages tile t+2 into (t+2)%3 (3 loads/
// thread); end-of-iter vmcnt(3) == tile t+1 landed, t+2 flying (never
// drains to 0, T4) + RAW s_barrier (NOT __syncthreads -- hipcc inserts
// vmcnt(0) lgkmcnt(0) before it, killing the pipeline; r8 lesson).
// Buffer-reuse safety: to reach the barrier every wave has issued its
// MFMAs, whose lgkm waits imply its ds_reads of buf t%3 completed; buf
// t%3 is only overwritten after the barrier (iter t+1's stages).
// Swizzle (round-2 measured 0 conflicts): 16B unit ^ ((row>>1)&3) on
// pre-swizzled GLOBAL source, linear LDS dest (m173); reads use
// kg ^ ((R>>1)&3).
//
// u-only LISTA with T = I - S:  u' = soft_thresh(T@u) + Wx
// mode 0: UnextOrWx = bf16(acc)                       (Wx GEMM; u1 = Wx)
// mode 1: UnextOrWx = bf16(soft_thresh(acc) + WxIn)
// mode 2: z = soft_thresh(acc); fused transpose-write Out[b][k][p]
// ---------------------------------------------------------------------------
__global__ __launch_bounds__(512, 4) void gemm_kernel(
    const bf16_t* __restrict__ A, const bf16_t* __restrict__ Bt,
    int Kd, int mode,
    const bf16_t* __restrict__ WxIn, bf16_t* __restrict__ UnextOrWx,
    float* __restrict__ Out, const float* __restrict__ thresh_p)
{
  __shared__ __align__(16) char smem[73728];
  bf16_t* lds = (bf16_t*)smem;           // buf stride 12288 elems; B at +8192

  const int tid = threadIdx.x;
  const int wid = tid >> 6, lane = tid & 63;
  const int wr = wid >> 1, wc = wid & 1;         // 4M x 2N wave grid
  const int lr = lane & 15, kg = lane >> 4;

  // XCD-chunked swizzle (grid 1024 % 8 == 0), N-fastest: 8 consecutive
  // logical blocks = one M-panel x all 8 N-tiles (share A panel; B=T 2MiB
  // L2-resident).
  const int per = gridDim.x >> 3;
  const int logical = (blockIdx.x & 7) * per + (blockIdx.x >> 3);
  const int tileN = (logical & 7) << 7;          // 0..896
  const int tileM = (logical >> 3) << 8;         // 0..32512
  const int NT = Kd >> 5;

  // Per-thread staging geometry (A: 2 rounds, B: 1 round of 16B units;
  // rows are 32 bf16 = 4 units).
  size_t offA[2]; int dstA[2];
  #pragma unroll
  for (int j = 0; j < 2; ++j) {
    const int f = j * 512 + tid;                 // 0..1023
    const int row = f >> 2, u = f & 3;
    const int ug = u ^ ((row >> 1) & 3);
    offA[j] = (size_t)(tileM + row) * Kd + ug * 8;
    dstA[j] = f * 8;
  }
  size_t offB; int dstB;
  {
    const int col = tid >> 2, u = tid & 3;
    const int ug = u ^ ((col >> 1) & 3);
    offB = (size_t)(tileN + col) * Kd + ug * 8;
    dstB = 8192 + tid * 8;
  }

  auto readA = [&](int mi, int bs) -> bf16x8 {
    const int R = wr * 64 + mi * 16 + lr;
    return *(const bf16x8*)(lds + bs + R * 32 + ((kg ^ ((R >> 1) & 3)) << 3));
  };
  auto readB = [&](int ni, int bs) -> bf16x8 {
    const int C = wc * 64 + ni * 16 + lr;
    return *(const bf16x8*)(lds + bs + 8192 + C * 32 + ((kg ^ ((C >> 1) & 3)) << 3));
  };

  f32x4 acc[4][4] = {};
  bf16x8 af[4], bfr[4];

  // Prologue: stage tiles 0 and 1 (3 loads each).
  GLOAD_LDS16(A + offA[0], lds + dstA[0]);
  GLOAD_LDS16(A + offA[1], lds + dstA[1]);
  GLOAD_LDS16(Bt + offB, lds + dstB);
  GLOAD_LDS16(A + offA[0] + 32, lds + 12288 + dstA[0]);
  GLOAD_LDS16(A + offA[1] + 32, lds + 12288 + dstA[1]);
  GLOAD_LDS16(Bt + offB + 32, lds + 12288 + dstB);
  asm volatile("s_waitcnt vmcnt(3)" ::: "memory");   // tile 0 landed
  __builtin_amdgcn_s_barrier();

  int buf = 0, sb3 = 2;                              // t%3, (t+2)%3
  for (int t = 0; t < NT; ++t) {
    const int bs = buf * 12288;
    const int sbs = sb3 * 12288;
    const int ts = (t + 2 < NT) ? t + 2 : t + 2 - NT;   // wrap refetch (benign)
    const size_t ko = (size_t)ts << 5;

    // Issue-early: 3 stage loads for tile t+2.
    GLOAD_LDS16(A + offA[0] + ko, lds + sbs + dstA[0]);
    GLOAD_LDS16(A + offA[1] + ko, lds + sbs + dstA[1]);
    GLOAD_LDS16(Bt + offB + ko, lds + sbs + dstB);

    // Fragments (plain LDS loads; compiler schedules counted lgkm waits).
    #pragma unroll
    for (int mi = 0; mi < 4; ++mi) af[mi] = readA(mi, bs);
    #pragma unroll
    for (int ni = 0; ni < 4; ++ni) bfr[ni] = readB(ni, bs);

    #pragma unroll
    for (int mi = 0; mi < 4; ++mi)
      #pragma unroll
      for (int ni = 0; ni < 4; ++ni)
        acc[mi][ni] = MFMA(af[mi], bfr[ni], acc[mi][ni]);

    asm volatile("s_waitcnt vmcnt(3)" ::: "memory");   // tile t+1 landed
    __builtin_amdgcn_s_barrier();                      // raw: no drain

    buf = (buf == 2) ? 0 : buf + 1;
    sb3 = (sb3 == 2) ? 0 : sb3 + 1;
  }

  const float th = *thresh_p;

  if (mode <= 1) {
    // Repack epilogue: canonical row-major bf16, 8B/lane full-line stores.
    asm volatile("s_waitcnt vmcnt(0)" ::: "memory");   // wrap stages landed
    __syncthreads();
    float* Tl = (float*)smem;                          // [32][132] f32
    #pragma unroll
    for (int c = 0; c < 8; ++c) {                      // 32-row chunks
      if (c) __syncthreads();
      if (wr == (c >> 1)) {
        #pragma unroll
        for (int mj = 0; mj < 2; ++mj) {
          const int mi = (c & 1) * 2 + mj;
          const int rl = mj * 16 + kg * 4;
          #pragma unroll
          for (int ni = 0; ni < 4; ++ni) {
            const int cl = wc * 64 + ni * 16 + lr;
            #pragma unroll
            for (int r = 0; r < 4; ++r)
              Tl[(rl + r) * 132 + cl] = acc[mi][ni][r];
          }
        }
      }
      __syncthreads();
      #pragma unroll
      for (int j = 0; j < 2; ++j) {
        const int f  = j * 512 + tid;                  // 0..1023
        const int rl = f >> 5;                         // 0..31
        const int c4 = (f & 31) * 4;                   // 0..124
        const f32x4 v = *(const f32x4*)&Tl[rl * 132 + c4];
        const int grow = tileM + c * 32 + rl;
        const size_t gidx = (size_t)grow * 1024 + tileN + c4;
        bf16x4 ov;
        if (mode == 1) {
          const bf16x4 wx = *(const bf16x4*)&WxIn[gidx];
          #pragma unroll
          for (int e = 0; e < 4; ++e) {
            const float a  = fabsf(v[e]) - th;
            const float zn = (a > 0.f) ? copysignf(a, v[e]) : 0.f;
            ov[e] = (bf16_t)(zn + (float)wx[e]);
          }
        } else {
          #pragma unroll
          for (int e = 0; e < 4; ++e) ov[e] = (bf16_t)v[e];
        }
        *(bf16x4*)&UnextOrWx[gidx] = ov;
      }
    }
  } else {
    // mode 2: z = st(acc), fused transpose via LDS -> Out[b][k][p], f32 16B.
    #pragma unroll
    for (int mi = 0; mi < 4; ++mi)
      #pragma unroll
      for (int ni = 0; ni < 4; ++ni)
        #pragma unroll
        for (int r = 0; r < 4; ++r) {
          const float v = acc[mi][ni][r];
          const float a = fabsf(v) - th;
          acc[mi][ni][r] = (a > 0.f) ? copysignf(a, v) : 0.f;
        }
    asm volatile("s_waitcnt vmcnt(0)" ::: "memory");
    __syncthreads();
    float* T = (float*)smem;                           // [32][260] f32
    const int    bb    = tileM >> 10;
    const size_t obase = (size_t)bb * 1048576 + (size_t)(tileM & 1023);
    #pragma unroll
    for (int ch = 0; ch < 4; ++ch) {                   // 32-k-col chunks
      if (ch) __syncthreads();
      if (wc == (ch >> 1)) {
        #pragma unroll
        for (int nj = 0; nj < 2; ++nj) {
          const int ni = (ch & 1) * 2 + nj;
          const int cp = nj * 16 + lr;                 // 0..31
          #pragma unroll
          for (int mi = 0; mi < 4; ++mi)
            #pragma unroll
            for (int r = 0; r < 4; ++r)
              T[cp * 260 + wr * 64 + mi * 16 + kg * 4 + r] = acc[mi][ni][r];
        }
      }
      __syncthreads();
      #pragma unroll
      for (int j = 0; j < 4; ++j) {
        const int f  = j * 512 + tid;                  // 0..2047
        const int cp = f >> 6;                         // 0..31
        const int p4 = (f & 63) * 4;                   // 0..252
        const f32x4 v = *(const f32x4*)&T[cp * 260 + p4];
        *(f32x4*)&Out[obase + (size_t)(tileN + ch * 32 + cp) * 1024 + p4] = v;
      }
    }
  }
}

__global__ void cast_f32_bf16_kernel(const float* __restrict__ src,
                                     bf16_t* __restrict__ dst, int n) {
  int i = blockIdx.x * blockDim.x + threadIdx.x;
  if (i < n) dst[i] = (bf16_t)src[i];
}

// T = I - S, cast to bf16. [1024][1024]
__global__ void make_T_kernel(const float* __restrict__ S,
                              bf16_t* __restrict__ T) {
  const int idx = blockIdx.x * blockDim.x + threadIdx.x;   // 0..1048575
  const int i = idx >> 10, j = idx & 1023;
  T[idx] = (bf16_t)(((i == j) ? 1.0f : 0.0f) - S[idx]);
}

// x [B][C=512][P=1024] f32 -> xt [b*1024+p][c] bf16  (32x32 tiled transpose)
__global__ void transpose_cast_x_kernel(const float* __restrict__ x,
                                        bf16_t* __restrict__ xt) {
  __shared__ float t[32][33];
  const int b  = blockIdx.z;
  const int p0 = blockIdx.x * 32;
  const int c0 = blockIdx.y * 32;
  const int tx = threadIdx.x, ty = threadIdx.y;
  #pragma unroll
  for (int i = 0; i < 32; i += 8)
    t[ty + i][tx] = x[((size_t)b * 512 + c0 + ty + i) * 1024 + p0 + tx];
  __syncthreads();
  #pragma unroll
  for (int i = 0; i < 32; i += 8)
    xt[((size_t)b * 1024 + p0 + ty + i) * 512 + c0 + tx] = (bf16_t)t[tx][ty + i];
}

__global__ void dict_norm_kernel(const float* __restrict__ dict,
                                 float* __restrict__ out) {
  const int row = blockIdx.x;       // 1024
  const int tid = threadIdx.x;      // 256
  const float* r = dict + (size_t)row * 512;
  float s = 0.f;
  for (int i = tid; i < 512; i += 256) { float v = r[i]; s += v * v; }
  #pragma unroll
  for (int off = 32; off > 0; off >>= 1) s += __shfl_down(s, off);
  __shared__ float ps[4];
  if ((tid & 63) == 0) ps[tid >> 6] = s;
  __syncthreads();
  const float inv = 1.0f / sqrtf(ps[0] + ps[1] + ps[2] + ps[3]);
  for (int i = tid; i < 512; i += 256) out[(size_t)row * 512 + i] = r[i] * inv;
}

extern "C" void kernel_launch(void* const* d_in, const int* in_sizes, int n_in,
                              void* d_out, int out_size, void* d_ws, size_t ws_size,
                              hipStream_t stream) {
  const float* x      = (const float*)d_in[0];  // [32,512,32,32]
  const float* dict   = (const float*)d_in[1];  // [1024,512]
  const float* W      = (const float*)d_in[2];  // [1024,512]
  const float* S      = (const float*)d_in[3];  // [1024,1024]
  const float* thresh = (const float*)d_in[4];  // scalar

  float* out = (float*)d_out;

  char* ws = (char*)d_ws;
  bf16_t* uA   = (bf16_t*)ws;                     //  67,108,864 B [32768][1024]
  bf16_t* uB   = (bf16_t*)(ws + 67108864);        //  67,108,864 B
  bf16_t* WxBf = (bf16_t*)(ws + 134217728);       //  67,108,864 B
  bf16_t* xt   = (bf16_t*)(ws + 201326592);       //  33,554,432 B [32768][512]
  bf16_t* Wbf  = (bf16_t*)(ws + 234881024);       //   1,048,576 B
  bf16_t* Tbf  = (bf16_t*)(ws + 235929600);       //   2,097,152 B (end 238,026,752)

  float* dnorm = out + 33554432;                  // dict_norm region (disjoint)

  cast_f32_bf16_kernel<<<dim3(2048), dim3(256), 0, stream>>>(W, Wbf, 524288);
  make_T_kernel<<<dim3(2048), dim3(512), 0, stream>>>(S, Tbf);
  transpose_cast_x_kernel<<<dim3(32, 16, 32), dim3(32, 8), 0, stream>>>(x, xt);
  dict_norm_kernel<<<dim3(1024), dim3(256), 0, stream>>>(dict, dnorm);

  // Wx_t = x_t @ W^T  -> WxBf  (u1 == Wx, read directly by step 1)
  gemm_kernel<<<dim3(1024), dim3(512), 0, stream>>>(
      xt, Wbf, 512, 0, nullptr, WxBf, nullptr, thresh);

  // steps 1..4: u' = soft_thresh(T@u) + Wx
  bf16_t* uc = WxBf; bf16_t* un = uA;
  for (int s = 0; s < 4; ++s) {
    gemm_kernel<<<dim3(1024), dim3(512), 0, stream>>>(
        uc, Tbf, 1024, 1, WxBf, un, nullptr, thresh);
    uc = un;
    un = (uc == uA) ? uB : uA;
  }
  // step 5: z = soft_thresh(T@u), fused transpose to out[b][k][p]
  gemm_kernel<<<dim3(1024), dim3(512), 0, stream>>>(
      uc, Tbf, 1024, 2, nullptr, nullptr, out, thresh);
}

// Round 10
// 541.370 us; speedup vs baseline: 1.0994x; 1.0177x over previous
//
#include <hip/hip_runtime.h>
#include <hip/hip_bf16.h>

typedef __bf16 bf16_t;
typedef __bf16 bf16x8 __attribute__((ext_vector_type(8)));
typedef float f32x4 __attribute__((ext_vector_type(4)));

#define GLOAD_LDS16(g, l)                                                      \
  __builtin_amdgcn_global_load_lds(                                            \
      (const __attribute__((address_space(1))) void*)(g),                      \
      (__attribute__((address_space(3))) void*)(l), 16, 0, 0)

#define MFMA(a, b, c) __builtin_amdgcn_mfma_f32_16x16x32_bf16((a), (b), (c), 0, 0, 0)

// ---------------------------------------------------------------------------
// ROUND 10: fat 64x128 wave-tiles on 256x256 block (LDS-ceiling fix) + BK=64
// (the r4-r9 empirical law: BK=32 => 3-4x HBM write amplification; BK=64 =>
// exact-ideal writes) + TW=T@W precompute so step-1 runs at K=512.
//
// Geometry: BM=BN=256, BK=64, 512 thr, 8 waves as 4M x 2N, wave-tile 64x128.
// FLOP/LDS-byte = 64*128/192 = 42.7 (was 32) -> LDS ceiling 64% MfmaUtil
// (was 47%). acc[4][8]=128 VGPR + frags ~50 -> ~210 regs, 2 waves/SIMD.
// LDS: 2 bufs x (A[256][64] 32KB + B[256][64] 32KB) = 128KB, 1 block/CU.
// Pipeline: iter t reads buf t&1, stages tile t+1 into buf (t+1)&1 with
// 8 loads/thread issued SPLIT (4 A early, 4 B mid) so they fly under the
// ~1000cy compute; end-of-iter vmcnt(0) + RAW s_barrier (2-buf forces the
// drain; r8 measured full drains ~= counted here, loads are L2-resident).
// Swizzle (measured 0 conflicts r2/r6): 16B unit ^ (row&7) on pre-swizzled
// GLOBAL source, linear LDS dest (m173); frag reads use (ks*4+kg)^(R&7).
//
// u-only LISTA with T = I - S:  u' = soft_thresh(T@u) + Wx
// mode 0: UnextOrWx = bf16(acc)             (Wx / TW GEMMs; Nc param stride)
// mode 1: UnextOrWx = bf16(soft_thresh(acc) + WxIn)
// mode 2: z = soft_thresh(acc); fused transpose-write Out[b][k][p]
// ---------------------------------------------------------------------------
__global__ __launch_bounds__(512, 2) void gemm_kernel(
    const bf16_t* __restrict__ A, const bf16_t* __restrict__ Bt,
    int Kd, int Nc, int mode,
    const bf16_t* __restrict__ WxIn, bf16_t* __restrict__ UnextOrWx,
    float* __restrict__ Out, const float* __restrict__ thresh_p)
{
  __shared__ __align__(16) char smem[131072];
  bf16_t* lds = (bf16_t*)smem;     // buf stride 32768 elems; B at +16384

  const int tid = threadIdx.x;
  const int wid = tid >> 6, lane = tid & 63;
  const int wr = wid >> 1, wc = wid & 1;         // 4M x 2N waves, 64x128 tiles
  const int lr = lane & 15, kg = lane >> 4;

  // XCD-chunked swizzle (grid % 8 == 0), N-fastest.
  const int per = gridDim.x >> 3;
  const int logical = (blockIdx.x & 7) * per + (blockIdx.x >> 3);
  const int ntn = Nc >> 8;
  const int tileN = (logical % ntn) << 8;
  const int tileM = (logical / ntn) << 8;
  const int NT = Kd >> 6;

  // Staging geometry: per K-tile A = 32KB = 2048 16B-units -> 4 loads/thread;
  // B same. Row = 64 bf16 = 8 units; unit ^ (row&7) pre-swizzle on source.
  int offA[4], offB[4], dstA[4], dstB[4];
  #pragma unroll
  for (int j = 0; j < 4; ++j) {
    const int f = j * 512 + tid;                 // 0..2047
    const int row = f >> 3, u = f & 7;
    const int ug = u ^ (row & 7);
    offA[j] = (tileM + row) * Kd + ug * 8;
    offB[j] = (tileN + row) * Kd + ug * 8;
    dstA[j] = f * 8;
    dstB[j] = 16384 + f * 8;
  }

  auto readA = [&](int mi, int ks, int bs) -> bf16x8 {
    const int R = wr * 64 + mi * 16 + lr;
    const int ul = (ks * 4 + kg) ^ (R & 7);
    return *(const bf16x8*)(lds + bs + R * 64 + ul * 8);
  };
  auto readB = [&](int ni, int ks, int bs) -> bf16x8 {
    const int C = wc * 128 + ni * 16 + lr;
    const int ul = (ks * 4 + kg) ^ (C & 7);
    return *(const bf16x8*)(lds + bs + 16384 + C * 64 + ul * 8);
  };

  f32x4 acc[4][8] = {};
  bf16x8 af[4], bfr[8];

  // Prologue: stage tile 0 into buf 0.
  #pragma unroll
  for (int j = 0; j < 4; ++j) GLOAD_LDS16(A + offA[j], lds + dstA[j]);
  #pragma unroll
  for (int j = 0; j < 4; ++j) GLOAD_LDS16(Bt + offB[j], lds + dstB[j]);
  asm volatile("s_waitcnt vmcnt(0)" ::: "memory");
  __builtin_amdgcn_s_barrier();

  for (int t = 0; t < NT; ++t) {
    const int bs  = (t & 1) << 15;
    const int sbs = bs ^ 32768;
    const int ts = (t + 1 < NT) ? t + 1 : 0;     // wrap refetch (benign)
    const int ko = ts << 6;

    // Stage A(t+1) early; it flies under both MFMA phases.
    GLOAD_LDS16(A + offA[0] + ko, lds + sbs + dstA[0]);
    GLOAD_LDS16(A + offA[1] + ko, lds + sbs + dstA[1]);
    GLOAD_LDS16(A + offA[2] + ko, lds + sbs + dstA[2]);
    GLOAD_LDS16(A + offA[3] + ko, lds + sbs + dstA[3]);

    // ks0: 12 ds_reads + 32 MFMA (compiler inserts counted lgkm waits)
    #pragma unroll
    for (int mi = 0; mi < 4; ++mi) af[mi] = readA(mi, 0, bs);
    #pragma unroll
    for (int ni = 0; ni < 8; ++ni) bfr[ni] = readB(ni, 0, bs);
    __builtin_amdgcn_s_setprio(1);
    #pragma unroll
    for (int mi = 0; mi < 4; ++mi)
      #pragma unroll
      for (int ni = 0; ni < 8; ++ni)
        acc[mi][ni] = MFMA(af[mi], bfr[ni], acc[mi][ni]);
    __builtin_amdgcn_s_setprio(0);

    // Stage B(t+1) mid-iteration.
    GLOAD_LDS16(Bt + offB[0] + ko, lds + sbs + dstB[0]);
    GLOAD_LDS16(Bt + offB[1] + ko, lds + sbs + dstB[1]);
    GLOAD_LDS16(Bt + offB[2] + ko, lds + sbs + dstB[2]);
    GLOAD_LDS16(Bt + offB[3] + ko, lds + sbs + dstB[3]);

    // ks1
    #pragma unroll
    for (int mi = 0; mi < 4; ++mi) af[mi] = readA(mi, 1, bs);
    #pragma unroll
    for (int ni = 0; ni < 8; ++ni) bfr[ni] = readB(ni, 1, bs);
    __builtin_amdgcn_s_setprio(1);
    #pragma unroll
    for (int mi = 0; mi < 4; ++mi)
      #pragma unroll
      for (int ni = 0; ni < 8; ++ni)
        acc[mi][ni] = MFMA(af[mi], bfr[ni], acc[mi][ni]);
    __builtin_amdgcn_s_setprio(0);

    // 2-buf: all 8 stage loads of t+1 must be LDS-visible to ALL waves.
    asm volatile("s_waitcnt vmcnt(0)" ::: "memory");
    __builtin_amdgcn_s_barrier();                // raw: no compiler drain
  }

  const float th = *thresh_p;

  if (mode <= 1) {
    // Repack epilogue: canonical row-major bf16, 16B/lane full-line stores.
    asm volatile("s_waitcnt vmcnt(0)" ::: "memory");  // wrap stages landed
    __syncthreads();
    float* Tl = (float*)smem;                         // [32][260] f32
    #pragma unroll
    for (int c = 0; c < 8; ++c) {                     // 32-row chunks
      if (c) __syncthreads();
      if (wr == (c >> 1)) {                           // 2 waves (wc=0,1) own it
        #pragma unroll
        for (int mj = 0; mj < 2; ++mj) {
          const int mi = (c & 1) * 2 + mj;
          const int rl = mj * 16 + kg * 4;
          #pragma unroll
          for (int ni = 0; ni < 8; ++ni) {
            const int cl = wc * 128 + ni * 16 + lr;
            #pragma unroll
            for (int r = 0; r < 4; ++r)
              Tl[(rl + r) * 260 + cl] = acc[mi][ni][r];
          }
        }
      }
      __syncthreads();
      #pragma unroll
      for (int j = 0; j < 2; ++j) {
        const int f  = j * 512 + tid;                 // 0..1023
        const int rl = f >> 5;                        // 0..31
        const int c8 = (f & 31) * 8;                  // 0..248
        float v[8];
        *(f32x4*)&v[0] = *(const f32x4*)&Tl[rl * 260 + c8];
        *(f32x4*)&v[4] = *(const f32x4*)&Tl[rl * 260 + c8 + 4];
        const int grow = tileM + c * 32 + rl;
        const size_t gidx = (size_t)grow * Nc + tileN + c8;
        bf16x8 ov;
        if (mode == 1) {
          const bf16x8 wx = *(const bf16x8*)&WxIn[gidx];
          #pragma unroll
          for (int e = 0; e < 8; ++e) {
            const float a  = fabsf(v[e]) - th;
            const float zn = (a > 0.f) ? copysignf(a, v[e]) : 0.f;
            ov[e] = (bf16_t)(zn + (float)wx[e]);
          }
        } else {
          #pragma unroll
          for (int e = 0; e < 8; ++e) ov[e] = (bf16_t)v[e];
        }
        *(bf16x8*)&UnextOrWx[gidx] = ov;
      }
    }
  } else {
    // mode 2: z = st(acc); fused transpose -> Out[b][k][p], f32 16B stores.
    #pragma unroll
    for (int mi = 0; mi < 4; ++mi)
      #pragma unroll
      for (int ni = 0; ni < 8; ++ni)
        #pragma unroll
        for (int r = 0; r < 4; ++r) {
          const float v = acc[mi][ni][r];
          const float a = fabsf(v) - th;
          acc[mi][ni][r] = (a > 0.f) ? copysignf(a, v) : 0.f;
        }
    asm volatile("s_waitcnt vmcnt(0)" ::: "memory");
    __syncthreads();
    float* Tl = (float*)smem;                         // [32][260] f32
    const int    bb    = tileM >> 10;
    const size_t obase = (size_t)bb * 1048576 + (size_t)(tileM & 1023);
    #pragma unroll
    for (int ch = 0; ch < 8; ++ch) {                  // 32-k-col chunks
      if (ch) __syncthreads();
      if (wc == (ch >> 2)) {                          // 4 waves (wr) own it
        #pragma unroll
        for (int nj = 0; nj < 2; ++nj) {
          const int ni = (ch & 3) * 2 + nj;
          const int cp = nj * 16 + lr;                // 0..31
          #pragma unroll
          for (int mi = 0; mi < 4; ++mi)
            #pragma unroll
            for (int r = 0; r < 4; ++r)
              Tl[cp * 260 + wr * 64 + mi * 16 + kg * 4 + r] = acc[mi][ni][r];
        }
      }
      __syncthreads();
      #pragma unroll
      for (int j = 0; j < 4; ++j) {
        const int f  = j * 512 + tid;                 // 0..2047
        const int cp = f >> 6;                        // 0..31
        const int p4 = (f & 63) * 4;                  // 0..252
        const f32x4 v = *(const f32x4*)&Tl[cp * 260 + p4];
        *(f32x4*)&Out[obase + (size_t)(tileN + ch * 32 + cp) * 1024 + p4] = v;
      }
    }
  }
}

__global__ void cast_f32_bf16_kernel(const float* __restrict__ src,
                                     bf16_t* __restrict__ dst, int n) {
  int i = blockIdx.x * blockDim.x + threadIdx.x;
  if (i < n) dst[i] = (bf16_t)src[i];
}

// T = I - S, cast to bf16. [1024][1024]
__global__ void make_T_kernel(const float* __restrict__ S,
                              bf16_t* __restrict__ T) {
  const int idx = blockIdx.x * blockDim.x + threadIdx.x;
  const int i = idx >> 10, j = idx & 1023;
  T[idx] = (bf16_t)(((i == j) ? 1.0f : 0.0f) - S[idx]);
}

// x [B][C=512][P=1024] f32 -> xt [b*1024+p][c] bf16
__global__ void transpose_cast_x_kernel(const float* __restrict__ x,
                                        bf16_t* __restrict__ xt) {
  __shared__ float t[32][33];
  const int b  = blockIdx.z;
  const int p0 = blockIdx.x * 32;
  const int c0 = blockIdx.y * 32;
  const int tx = threadIdx.x, ty = threadIdx.y;
  #pragma unroll
  for (int i = 0; i < 32; i += 8)
    t[ty + i][tx] = x[((size_t)b * 512 + c0 + ty + i) * 1024 + p0 + tx];
  __syncthreads();
  #pragma unroll
  for (int i = 0; i < 32; i += 8)
    xt[((size_t)b * 1024 + p0 + ty + i) * 512 + c0 + tx] = (bf16_t)t[tx][ty + i];
}

// Wt[c][j] = W[j][c], f32 [1024][512] -> bf16 [512][1024]
__global__ void transpose_cast_w_kernel(const float* __restrict__ W,
                                        bf16_t* __restrict__ Wt) {
  __shared__ float t[32][33];
  const int j0 = blockIdx.x * 32;
  const int c0 = blockIdx.y * 32;
  const int tx = threadIdx.x, ty = threadIdx.y;
  #pragma unroll
  for (int i = 0; i < 32; i += 8)
    t[ty + i][tx] = W[(size_t)(j0 + ty + i) * 512 + c0 + tx];
  __syncthreads();
  #pragma unroll
  for (int i = 0; i < 32; i += 8)
    Wt[(size_t)(c0 + ty + i) * 1024 + j0 + tx] = (bf16_t)t[tx][ty + i];
}

__global__ void dict_norm_kernel(const float* __restrict__ dict,
                                 float* __restrict__ out) {
  const int row = blockIdx.x;
  const int tid = threadIdx.x;
  const float* r = dict + (size_t)row * 512;
  float s = 0.f;
  for (int i = tid; i < 512; i += 256) { float v = r[i]; s += v * v; }
  #pragma unroll
  for (int off = 32; off > 0; off >>= 1) s += __shfl_down(s, off);
  __shared__ float ps[4];
  if ((tid & 63) == 0) ps[tid >> 6] = s;
  __syncthreads();
  const float inv = 1.0f / sqrtf(ps[0] + ps[1] + ps[2] + ps[3]);
  for (int i = tid; i < 512; i += 256) out[(size_t)row * 512 + i] = r[i] * inv;
}

extern "C" void kernel_launch(void* const* d_in, const int* in_sizes, int n_in,
                              void* d_out, int out_size, void* d_ws, size_t ws_size,
                              hipStream_t stream) {
  const float* x      = (const float*)d_in[0];  // [32,512,32,32]
  const float* dict   = (const float*)d_in[1];  // [1024,512]
  const float* W      = (const float*)d_in[2];  // [1024,512]
  const float* S      = (const float*)d_in[3];  // [1024,1024]
  const float* thresh = (const float*)d_in[4];  // scalar

  float* out = (float*)d_out;

  char* ws = (char*)d_ws;
  bf16_t* uA   = (bf16_t*)ws;                     //  67,108,864 B [32768][1024]
  bf16_t* uB   = (bf16_t*)(ws + 67108864);        //  67,108,864 B
  bf16_t* WxBf = (bf16_t*)(ws + 134217728);       //  67,108,864 B
  bf16_t* xt   = (bf16_t*)(ws + 201326592);       //  33,554,432 B [32768][512]
  bf16_t* Wbf  = (bf16_t*)(ws + 234881024);       //   1,048,576 B
  bf16_t* Tbf  = (bf16_t*)(ws + 235929600);       //   2,097,152 B (end 238,026,752)

  // Temporaries in d_out's z-region (overwritten by mode-2 at the end).
  bf16_t* WtBf = (bf16_t*)out;                    //   1,048,576 B [512][1024]
  bf16_t* TWbf = WtBf + 524288;                   //   1,048,576 B [1024][512]
  float* dnorm = out + 33554432;                  // dict_norm region (disjoint)

  cast_f32_bf16_kernel<<<dim3(2048), dim3(256), 0, stream>>>(W, Wbf, 524288);
  make_T_kernel<<<dim3(2048), dim3(512), 0, stream>>>(S, Tbf);
  transpose_cast_x_kernel<<<dim3(32, 16, 32), dim3(32, 8), 0, stream>>>(x, xt);
  transpose_cast_w_kernel<<<dim3(32, 16), dim3(32, 8), 0, stream>>>(W, WtBf);
  dict_norm_kernel<<<dim3(1024), dim3(256), 0, stream>>>(dict, dnorm);

  // TW = T @ W  (M=1024, Nc=512, Kd=1024): grid 4x2 = 8 blocks, mode 0.
  gemm_kernel<<<dim3(8), dim3(512), 0, stream>>>(
      Tbf, WtBf, 1024, 512, 0, nullptr, TWbf, nullptr, thresh);

  // Wx = xt @ W^T  (Kd=512) -> WxBf
  gemm_kernel<<<dim3(512), dim3(512), 0, stream>>>(
      xt, Wbf, 512, 1024, 0, nullptr, WxBf, nullptr, thresh);

  // step 1 at K=512: u2 = st(TW @ x) + Wx
  gemm_kernel<<<dim3(512), dim3(512), 0, stream>>>(
      xt, TWbf, 512, 1024, 1, WxBf, uA, nullptr, thresh);

  // steps 2..4: u' = st(T@u) + Wx
  bf16_t* uc = uA; bf16_t* un = uB;
  for (int s = 0; s < 3; ++s) {
    gemm_kernel<<<dim3(512), dim3(512), 0, stream>>>(
        uc, Tbf, 1024, 1024, 1, WxBf, un, nullptr, thresh);
    bf16_t* tmp = uc; uc = un; un = tmp;
  }
  // step 5: z = st(T@u), fused transpose to out[b][k][p]
  gemm_kernel<<<dim3(512), dim3(512), 0, stream>>>(
      uc, Tbf, 1024, 1024, 2, nullptr, nullptr, out, thresh);
}